// Round 1
// baseline (3494.575 us; speedup 1.0000x reference)
//
#include <hip/hip_runtime.h>

// ---------------------------------------------------------------------------
// SensorClassifierDualEncoder on MI355X (gfx950)
// B=32768, S=5, D=512, E=256, H=4 (DH=64), F=2048, L=2, C=5. N_TOK = B*S.
//
// Pipeline (all GEMMs bf16-MFMA 16x16x32, fp32 accum):
//   cvt weights+x -> bf16 | embed(gps)->t32, embed(ang)->h32 | select->h32,h16
//   per layer: qkv GEMM -> R | attn(LDS) -> o16 | proj GEMM -> t32 |
//              ln_res -> h32,h16 | FFN (4 token chunks, mid in R) -> t32 |
//              ln_res -> h32,h16
//   fc1 GEMM -> t32 (z1) | head2 (fp32) -> d_out
//
// Workspace layout (bytes):
//   [0, 6.1MB)      bf16 weights pool
//   [8MB, +252MB)   R: x16 (168MB) -> qkv16 (252MB) -> ffn-mid chunk (168MB)
//   then h16 (84MB), h32 (168MB fp32 master), t32 (168MB pre-LN sums),
//   o16 (84MB).  Total = 763,363,328 B.
// ---------------------------------------------------------------------------

#define N_TOK 163840
#define NBATCH 32768

typedef __attribute__((ext_vector_type(8))) short bfrag;   // 8 bf16 (4 VGPRs)
typedef __attribute__((ext_vector_type(4))) float f32x4;

__device__ __forceinline__ float bf2f(ushort u) {
  return __builtin_bit_cast(float, (uint)u << 16);
}
__device__ __forceinline__ ushort f2bf(float f) {
  uint u = __builtin_bit_cast(uint, f);
  return (ushort)((u + 0x7FFFu + ((u >> 16) & 1u)) >> 16);   // RNE
}

// --------------------------- fp32 -> bf16 cast -----------------------------
__global__ __launch_bounds__(256) void cvt_kernel(const float* __restrict__ in,
                                                  ushort* __restrict__ out, int n4) {
  int i = blockIdx.x * 256 + threadIdx.x;
  if (i >= n4) return;
  float4 v = ((const float4*)in)[i];
  ushort4 o;
  o.x = f2bf(v.x); o.y = f2bf(v.y); o.z = f2bf(v.z); o.w = f2bf(v.w);
  ((ushort4*)out)[i] = o;
}

// --------------------------- generic MFMA GEMM -----------------------------
// C[M,O] = A[M,K] * W[O,K]^T + bias;  M%128==0, K%32==0, O%128==0.
// block 256 thr = 4 waves; tile 128x128, BK=32; wave -> 64x64 quadrant.
enum { EPI_F32 = 0, EPI_F32_RELU = 1, EPI_BF16 = 2, EPI_BF16_RELU = 3 };

template <int EPI>
__global__ __launch_bounds__(256) void gemm_bt(const ushort* __restrict__ A,
                                               const ushort* __restrict__ W,
                                               const float* __restrict__ bias,
                                               void* __restrict__ outp,
                                               int M, int K, int O) {
  __shared__ ushort As[128][40];   // +8 pad: 80B row stride -> 2-way bank alias (free)
  __shared__ ushort Bs[128][40];
  const int tid = threadIdx.x;
  const int wave = tid >> 6, lane = tid & 63;
  const int bm = blockIdx.y, bn = blockIdx.x;
  const int wm = (wave & 1) << 6, wn = (wave >> 1) << 6;
  const int srow = tid >> 2;            // staging row 0..63 (and +64)
  const int scol = (tid & 3) << 3;      // staging col 0,8,16,24

  const ushort* Abase = A + (size_t)bm * 128 * K + (size_t)srow * K + scol;
  const ushort* Wbase = W + (size_t)bn * 128 * K + (size_t)srow * K + scol;

  f32x4 acc[4][4];
#pragma unroll
  for (int i = 0; i < 4; i++)
#pragma unroll
    for (int j = 0; j < 4; j++) acc[i][j] = {0.f, 0.f, 0.f, 0.f};

  const int fr = lane & 15;             // fragment row/col within 16-tile
  const int fkb = (lane >> 4) << 3;     // fragment k offset: quad*8

  for (int k0 = 0; k0 < K; k0 += 32) {
    __syncthreads();
    uint4 a0 = *(const uint4*)(Abase + k0);
    uint4 a1 = *(const uint4*)(Abase + k0 + (size_t)64 * K);
    uint4 b0 = *(const uint4*)(Wbase + k0);
    uint4 b1 = *(const uint4*)(Wbase + k0 + (size_t)64 * K);
    *(uint4*)&As[srow][scol]      = a0;
    *(uint4*)&As[srow + 64][scol] = a1;
    *(uint4*)&Bs[srow][scol]      = b0;
    *(uint4*)&Bs[srow + 64][scol] = b1;
    __syncthreads();
    bfrag af[4], bf_[4];
#pragma unroll
    for (int i = 0; i < 4; i++) af[i] = *(const bfrag*)&As[wm + i * 16 + fr][fkb];
#pragma unroll
    for (int j = 0; j < 4; j++) bf_[j] = *(const bfrag*)&Bs[wn + j * 16 + fr][fkb];
#pragma unroll
    for (int i = 0; i < 4; i++)
#pragma unroll
      for (int j = 0; j < 4; j++)
        acc[i][j] = __builtin_amdgcn_mfma_f32_16x16x32_bf16(af[i], bf_[j], acc[i][j], 0, 0, 0);
  }

  // epilogue: C/D layout col=lane&15, row=(lane>>4)*4+r
  const int cr = (lane >> 4) << 2;
  const int cc = lane & 15;
#pragma unroll
  for (int j = 0; j < 4; j++) {
    const int col = bn * 128 + wn + j * 16 + cc;
    const float bv = bias[col];
#pragma unroll
    for (int i = 0; i < 4; i++) {
      const size_t rbase = (size_t)(bm * 128 + wm + i * 16 + cr) * O + col;
#pragma unroll
      for (int r = 0; r < 4; r++) {
        float v = acc[i][j][r] + bv;
        if (EPI == EPI_F32_RELU || EPI == EPI_BF16_RELU) v = fmaxf(v, 0.f);
        if (EPI == EPI_F32 || EPI == EPI_F32_RELU)
          ((float*)outp)[rbase + (size_t)r * O] = v;
        else
          ((ushort*)outp)[rbase + (size_t)r * O] = f2bf(v);
      }
    }
  }
}

// --------------------------- expert select ---------------------------------
// h32 holds relu(ang); gbuf holds relu(gps); pick per token, write h32+h16.
__global__ __launch_bounds__(256) void select_kernel(const float* __restrict__ gbuf,
                                                     float* __restrict__ h32,
                                                     ushort* __restrict__ h16,
                                                     const int* __restrict__ stype) {
  const size_t i4 = (size_t)blockIdx.x * 256 + threadIdx.x;
  const int sel = stype[i4 >> 6];       // 64 float4-groups per 256-wide token row
  float4 gv = *(const float4*)&gbuf[i4 * 4];
  float4 av = *(const float4*)&h32[i4 * 4];
  float4 h = (sel == 0) ? gv : av;
  *(float4*)&h32[i4 * 4] = h;
  ushort4 hb = {f2bf(h.x), f2bf(h.y), f2bf(h.z), f2bf(h.w)};
  *(ushort4*)&h16[i4 * 4] = hb;
}

// --------------------------- attention (S=5) -------------------------------
// 8 batches per block in LDS; scores/softmax/AV in fp32; out bf16 [N,256].
__global__ __launch_bounds__(256) void attn_kernel(const ushort* __restrict__ qkv,
                                                   ushort* __restrict__ o16) {
  __shared__ ushort s_qkv[8 * 5 * 768];   // 61440 B
  __shared__ float s_att[8 * 4 * 25];
  const int tid = threadIdx.x;
  const size_t gbase = (size_t)blockIdx.x * (8 * 5 * 768);
#pragma unroll
  for (int t = 0; t < 15; t++) {
    int i = tid + t * 256;
    *(uint4*)&s_qkv[i * 8] = *(const uint4*)(qkv + gbase + (size_t)i * 8);
  }
  __syncthreads();
  // scores: 8*4*25 = 800 dot-64s
  for (int idx = tid; idx < 800; idx += 256) {
    int b = idx / 100, r = idx - b * 100;
    int h = r / 25, ij = r - h * 25;
    int i = ij / 5, j = ij - i * 5;
    const ushort* qp = &s_qkv[(b * 5 + i) * 768 + h * 64];
    const ushort* kp = &s_qkv[(b * 5 + j) * 768 + 256 + h * 64];
    float s = 0.f;
#pragma unroll
    for (int d = 0; d < 64; d += 2) {
      uint qw = *(const uint*)&qp[d];
      uint kw = *(const uint*)&kp[d];
      s += bf2f((ushort)(qw & 0xffffu)) * bf2f((ushort)(kw & 0xffffu));
      s += bf2f((ushort)(qw >> 16)) * bf2f((ushort)(kw >> 16));
    }
    s_att[idx] = s * 0.125f;   // 1/sqrt(64)
  }
  __syncthreads();
  if (tid < 160) {             // softmax over j for each (b,h,i)
    float* sp = &s_att[tid * 5];
    float m = fmaxf(fmaxf(fmaxf(sp[0], sp[1]), fmaxf(sp[2], sp[3])), sp[4]);
    float e0 = __expf(sp[0] - m), e1 = __expf(sp[1] - m), e2 = __expf(sp[2] - m);
    float e3 = __expf(sp[3] - m), e4 = __expf(sp[4] - m);
    float inv = 1.f / (e0 + e1 + e2 + e3 + e4);
    sp[0] = e0 * inv; sp[1] = e1 * inv; sp[2] = e2 * inv; sp[3] = e3 * inv; sp[4] = e4 * inv;
  }
  __syncthreads();
  const size_t obase = (size_t)blockIdx.x * (8 * 5 * 256);
#pragma unroll
  for (int t = 0; t < 40; t++) {         // 10240 outputs
    int idx = t * 256 + tid;
    int d = idx & 63;
    int rest = idx >> 6;
    int h = rest & 3; rest >>= 2;
    int i = rest % 5, b = rest / 5;
    const float* ap = &s_att[(b * 4 + h) * 25 + i * 5];
    const ushort* vp = &s_qkv[(b * 5) * 768 + 512 + h * 64 + d];
    float o = 0.f;
#pragma unroll
    for (int j = 0; j < 5; j++) o += ap[j] * bf2f(vp[j * 768]);
    o16[obase + (size_t)((b * 5 + i) * 256 + h * 64 + d)] = f2bf(o);
  }
}

// --------------------------- residual + LayerNorm --------------------------
// u = t + h32; LN(u)*g + b -> h32 (fp32 master) and h16 (bf16). 1 wave/row.
__global__ __launch_bounds__(256) void ln_res_kernel(const float* __restrict__ t,
                                                     float* __restrict__ h32,
                                                     ushort* __restrict__ h16,
                                                     const float* __restrict__ g,
                                                     const float* __restrict__ b) {
  const int wave = threadIdx.x >> 6, lane = threadIdx.x & 63;
  const size_t row = (size_t)blockIdx.x * 4 + wave;
  const size_t off = row * 256 + lane * 4;
  float4 tv = *(const float4*)&t[off];
  float4 hv = *(const float4*)&h32[off];
  float4 u = {tv.x + hv.x, tv.y + hv.y, tv.z + hv.z, tv.w + hv.w};
  float s = u.x + u.y + u.z + u.w;
  float sq = u.x * u.x + u.y * u.y + u.z * u.z + u.w * u.w;
#pragma unroll
  for (int o = 32; o > 0; o >>= 1) { s += __shfl_xor(s, o); sq += __shfl_xor(sq, o); }
  float mean = s * 0.00390625f;
  float var = sq * 0.00390625f - mean * mean;
  float rstd = rsqrtf(var + 1e-5f);
  float4 gv = *(const float4*)&g[lane * 4];
  float4 bv = *(const float4*)&b[lane * 4];
  float4 y = {(u.x - mean) * rstd * gv.x + bv.x, (u.y - mean) * rstd * gv.y + bv.y,
              (u.z - mean) * rstd * gv.z + bv.z, (u.w - mean) * rstd * gv.w + bv.w};
  *(float4*)&h32[off] = y;
  ushort4 hb = {f2bf(y.x), f2bf(y.y), f2bf(y.z), f2bf(y.w)};
  *(ushort4*)&h16[off] = hb;
}

// --------------------------- head: fc2 + out (fp32) ------------------------
__global__ __launch_bounds__(256) void head2_kernel(const float* __restrict__ z1,
                                                    const float* __restrict__ fc2w,
                                                    const float* __restrict__ fc2b,
                                                    const float* __restrict__ outw,
                                                    const float* __restrict__ outb,
                                                    float* __restrict__ out) {
  __shared__ float s_z2[4][64];
  const int wave = threadIdx.x >> 6, lane = threadIdx.x & 63;
  const int b = blockIdx.x * 4 + wave;
  const float* z = z1 + (size_t)b * 128;
  float acc = fc2b[lane];
#pragma unroll 8
  for (int k = 0; k < 128; k++) acc += z[k] * fc2w[lane * 128 + k];
  s_z2[wave][lane] = acc;
  __syncthreads();
  if (lane < 5) {
    const float* zz = s_z2[wave];
    float o = outb[lane];
#pragma unroll 8
    for (int k = 0; k < 64; k++) o += zz[k] * outw[lane * 64 + k];
    out[(size_t)b * 5 + lane] = o;
  }
}

// ---------------------------------------------------------------------------
extern "C" void kernel_launch(void* const* d_in, const int* in_sizes, int n_in,
                              void* d_out, int out_size, void* d_ws, size_t ws_size,
                              hipStream_t stream) {
  const float* x       = (const float*)d_in[0];
  const int*   stype   = (const int*)d_in[1];
  const float* gps_w   = (const float*)d_in[2];
  const float* gps_b   = (const float*)d_in[3];
  const float* ang_w   = (const float*)d_in[4];
  const float* ang_b   = (const float*)d_in[5];
  const float* qkv_w   = (const float*)d_in[6];
  const float* qkv_b   = (const float*)d_in[7];
  const float* attn_ow = (const float*)d_in[8];
  const float* attn_ob = (const float*)d_in[9];
  const float* ln1_g   = (const float*)d_in[10];
  const float* ln1_b   = (const float*)d_in[11];
  const float* ff1_w   = (const float*)d_in[12];
  const float* ff1_b   = (const float*)d_in[13];
  const float* ff2_w   = (const float*)d_in[14];
  const float* ff2_b   = (const float*)d_in[15];
  const float* fc1_w   = (const float*)d_in[16 + 2];  // index 18
  const float* fc1_b   = (const float*)d_in[19];
  const float* fc2_w   = (const float*)d_in[20];
  const float* fc2_b   = (const float*)d_in[21];
  const float* out_w   = (const float*)d_in[22];
  const float* out_b   = (const float*)d_in[23];
  const float* ln2_g   = (const float*)d_in[16];
  const float* ln2_b   = (const float*)d_in[17];

  char* ws = (char*)d_ws;
  const size_t NEED = 763363328ull;
  if (ws_size < NEED) return;  // workspace too small -> visible failure

  // bf16 weight pool
  ushort* w_gps  = (ushort*)ws;                 // 131072
  ushort* w_ang  = w_gps + 131072;              // 131072
  ushort* w_qkv  = w_ang + 131072;              // 393216 (L*768*256)
  ushort* w_attn = w_qkv + 393216;              // 131072 (L*256*256)
  ushort* w_ff1  = w_attn + 131072;             // 1048576 (L*2048*256)
  ushort* w_ff2  = w_ff1 + 1048576;             // 1048576 (L*256*2048)
  ushort* w_fc1  = w_ff2 + 1048576;             // 163840

  ushort* R16 = (ushort*)(ws + (size_t)(8u << 20));                 // 252MB region
  ushort* h16 = (ushort*)(ws + 8388608ull + 251658240ull);
  float*  h32 = (float*)(ws + 8388608ull + 251658240ull + 83886080ull);
  float*  t32 = (float*)(ws + 8388608ull + 251658240ull + 83886080ull + 167772160ull);
  ushort* o16 = (ushort*)(ws + 8388608ull + 251658240ull + 83886080ull + 335544320ull);

  auto cvt = [&](const float* src, ushort* dst, int n4) {
    cvt_kernel<<<(n4 + 255) / 256, 256, 0, stream>>>(src, dst, n4);
  };
  cvt(gps_w, w_gps, 32768);
  cvt(ang_w, w_ang, 32768);
  cvt(qkv_w, w_qkv, 98304);
  cvt(attn_ow, w_attn, 32768);
  cvt(ff1_w, w_ff1, 262144);
  cvt(ff2_w, w_ff2, 262144);
  cvt(fc1_w, w_fc1, 40960);
  cvt(x, R16, 20971520);   // x16 lives in R during embed

  // dual-expert embed: relu(gps)->t32, relu(ang)->h32, select->h32/h16
  gemm_bt<EPI_F32_RELU><<<dim3(2, 1280), 256, 0, stream>>>(R16, w_gps, gps_b, t32, N_TOK, 512, 256);
  gemm_bt<EPI_F32_RELU><<<dim3(2, 1280), 256, 0, stream>>>(R16, w_ang, ang_b, h32, N_TOK, 512, 256);
  select_kernel<<<40960, 256, 0, stream>>>(t32, h32, h16, stype);

  for (int l = 0; l < 2; l++) {
    gemm_bt<EPI_BF16><<<dim3(6, 1280), 256, 0, stream>>>(h16, w_qkv + l * 196608, qkv_b + l * 768,
                                                         R16, N_TOK, 256, 768);
    attn_kernel<<<4096, 256, 0, stream>>>(R16, o16);
    gemm_bt<EPI_F32><<<dim3(2, 1280), 256, 0, stream>>>(o16, w_attn + l * 65536, attn_ob + l * 256,
                                                        t32, N_TOK, 256, 256);
    ln_res_kernel<<<40960, 256, 0, stream>>>(t32, h32, h16, ln1_g + l * 256, ln1_b + l * 256);
    for (int c = 0; c < 4; c++) {   // FFN in 4 token chunks; mid tensor reuses R
      gemm_bt<EPI_BF16_RELU><<<dim3(16, 320), 256, 0, stream>>>(
          h16 + (size_t)c * 40960 * 256, w_ff1 + l * 524288, ff1_b + l * 2048, R16, 40960, 256, 2048);
      gemm_bt<EPI_F32><<<dim3(2, 320), 256, 0, stream>>>(
          R16, w_ff2 + l * 524288, ff2_b + l * 256, t32 + (size_t)c * 40960 * 256, 40960, 2048, 256);
    }
    ln_res_kernel<<<40960, 256, 0, stream>>>(t32, h32, h16, ln2_g + l * 256, ln2_b + l * 256);
  }

  // head: fc1 (bf16 MFMA) -> z1 in t32; fc2+out in fp32
  gemm_bt<EPI_F32><<<dim3(1, 256), 256, 0, stream>>>(h16, w_fc1, fc1_b, t32, NBATCH, 1280, 128);
  head2_kernel<<<8192, 256, 0, stream>>>(t32, fc2_w, fc2_b, out_w, out_b, (float*)d_out);
}